// Round 2
// baseline (601.497 us; speedup 1.0000x reference)
//
#include <hip/hip_runtime.h>
#include <hip/hip_bf16.h>

typedef short short8 __attribute__((ext_vector_type(8)));
typedef float float4v __attribute__((ext_vector_type(4)));

#define MFMA(a, b, c) __builtin_amdgcn_mfma_f32_16x16x32_bf16((a), (b), (c), 0, 0, 0)

static __device__ __forceinline__ unsigned short f2bf(float f) {
    union { float f; unsigned u; } v; v.f = f;
    unsigned r = (v.u + 0x7fffu + ((v.u >> 16) & 1u)) >> 16;
    return (unsigned short)r;
}
static __device__ __forceinline__ float bf2f(unsigned short h) {
    union { unsigned u; float f; } v; v.u = ((unsigned)h) << 16;
    return v.f;
}

// ---------------------------------------------------------------------------
// Kernel 0: weights fp32 -> bf16.
//   Whi[384][256]: rows 0..63=Wq, 64..127=Wk, 128..383=Wv
//   Wlo[128][256]: lo-part for Wq,Wk rows only (split-bf16 precision path)
// ---------------------------------------------------------------------------
__global__ void wcvt(const float* __restrict__ Wq, const float* __restrict__ Wk,
                     const float* __restrict__ Wv,
                     unsigned short* __restrict__ Whi, unsigned short* __restrict__ Wlo) {
    int idx = blockIdx.x * 256 + threadIdx.x;
    if (idx >= 384 * 256) return;
    int row = idx >> 8, c = idx & 255;
    float f;
    if (row < 64)       f = Wq[row * 256 + c];
    else if (row < 128) f = Wk[(row - 64) * 256 + c];
    else                f = Wv[(row - 128) * 256 + c];
    unsigned short hi = f2bf(f);
    Whi[idx] = hi;
    if (row < 128) Wlo[idx] = f2bf(f - bf2f(hi));
}

// ---------------------------------------------------------------------------
// Kernel 1: projections. Per block: batch b, n-tile of 64.
//   q,k as hi/lo bf16 pairs [N][64]; v single bf16 [C][N].
//   q/k GEMM uses split-bf16: Whi*xhi + Whi*xlo + Wlo*xhi  (~fp32 accurate)
// ---------------------------------------------------------------------------
__global__ __launch_bounds__(256) void proj(
        const float* __restrict__ x, const unsigned short* __restrict__ Whi,
        const unsigned short* __restrict__ Wlo,
        const float* __restrict__ bq, const float* __restrict__ bk,
        const float* __restrict__ bv,
        unsigned short* __restrict__ qhi_ws, unsigned short* __restrict__ qlo_ws,
        unsigned short* __restrict__ khi_ws, unsigned short* __restrict__ klo_ws,
        unsigned short* __restrict__ vws) {
    __shared__ unsigned short XThi[64 * 264];  // [n][c] bf16 hi, pitch 264
    __shared__ unsigned short XTlo[64 * 264];  // [n][c] bf16 lo

    const int tid = threadIdx.x;
    const int b  = blockIdx.x >> 7;
    const int n0 = (blockIdx.x & 127) << 6;
    const float* xb = x + b * 2097152;  // [256][8192]

    // Stage X^T tile: 64 n x 256 c (transpose + hi/lo split during staging)
    for (int p = 0; p < 16; ++p) {
        int idx = p * 256 + tid;
        int c = idx >> 4, nq = idx & 15;
        float4v xv = *reinterpret_cast<const float4v*>(xb + c * 8192 + n0 + nq * 4);
#pragma unroll
        for (int q = 0; q < 4; ++q) {
            unsigned short hi = f2bf(xv[q]);
            XThi[(nq * 4 + q) * 264 + c] = hi;
            XTlo[(nq * 4 + q) * 264 + c] = f2bf(xv[q] - bf2f(hi));
        }
    }
    __syncthreads();

    const int lane = tid & 63, w = tid >> 6;
    const int quad = lane >> 4, l16 = lane & 15;

    // ---- GEMM1: Y^T[n][o] for o in [0,128)  (q then k), split-bf16 ----
    short8 aXhi[8], aXlo[8];
#pragma unroll
    for (int ks = 0; ks < 8; ++ks) {
        aXhi[ks] = *reinterpret_cast<const short8*>(&XThi[(w * 16 + l16) * 264 + ks * 32 + quad * 8]);
        aXlo[ks] = *reinterpret_cast<const short8*>(&XTlo[(w * 16 + l16) * 264 + ks * 32 + quad * 8]);
    }

#pragma unroll
    for (int ot = 0; ot < 8; ++ot) {
        float4v acc = {0.f, 0.f, 0.f, 0.f};
#pragma unroll
        for (int ks = 0; ks < 8; ++ks) {
            short8 bwhi = *reinterpret_cast<const short8*>(&Whi[(ot * 16 + l16) * 256 + ks * 32 + quad * 8]);
            short8 bwlo = *reinterpret_cast<const short8*>(&Wlo[(ot * 16 + l16) * 256 + ks * 32 + quad * 8]);
            acc = MFMA(aXhi[ks], bwhi, acc);
            acc = MFMA(aXlo[ks], bwhi, acc);
            acc = MFMA(aXhi[ks], bwlo, acc);
        }
        int o = ot * 16 + l16;
        float bias = (ot < 4) ? bq[o] : bk[o - 64];
#pragma unroll
        for (int r = 0; r < 4; ++r) {
            int n = n0 + w * 16 + quad * 4 + r;
            float y = acc[r] + bias;
            unsigned short hi = f2bf(y);
            unsigned short lo = f2bf(y - bf2f(hi));
            if (ot < 4) {
                qhi_ws[(b * 8192 + n) * 64 + o] = hi;
                qlo_ws[(b * 8192 + n) * 64 + o] = lo;
            } else {
                khi_ws[(b * 8192 + n) * 64 + (o - 64)] = hi;
                klo_ws[(b * 8192 + n) * 64 + (o - 64)] = lo;
            }
        }
    }

    // ---- GEMM2: V[c][n], wave owns 64 c rows (single bf16) ----
    float4v acc2[4][4];
#pragma unroll
    for (int mt = 0; mt < 4; ++mt)
#pragma unroll
        for (int nt = 0; nt < 4; ++nt) acc2[mt][nt] = (float4v){0.f, 0.f, 0.f, 0.f};

#pragma unroll
    for (int ks = 0; ks < 8; ++ks) {
        short8 aW[4], bX[4];
#pragma unroll
        for (int mt = 0; mt < 4; ++mt)
            aW[mt] = *reinterpret_cast<const short8*>(&Whi[(128 + w * 64 + mt * 16 + l16) * 256 + ks * 32 + quad * 8]);
#pragma unroll
        for (int nt = 0; nt < 4; ++nt)
            bX[nt] = *reinterpret_cast<const short8*>(&XThi[(nt * 16 + l16) * 264 + ks * 32 + quad * 8]);
#pragma unroll
        for (int mt = 0; mt < 4; ++mt)
#pragma unroll
            for (int nt = 0; nt < 4; ++nt)
                acc2[mt][nt] = MFMA(aW[mt], bX[nt], acc2[mt][nt]);
    }
#pragma unroll
    for (int mt = 0; mt < 4; ++mt) {
#pragma unroll
        for (int r = 0; r < 4; ++r) {
            int c = w * 64 + mt * 16 + quad * 4 + r;
            float bias = bv[c];
#pragma unroll
            for (int nt = 0; nt < 4; ++nt)
                vws[(b * 256 + c) * 8192 + n0 + nt * 16 + l16] = f2bf(acc2[mt][nt][r] + bias);
        }
    }
}

// ---------------------------------------------------------------------------
// Kernel 2: flash attention + residual.
// Block: (b, 64-row i-tile). 4 waves. i-split QK/softmax, c-split PV.
// QK^T uses split-bf16 (hi*hi + lo*hi + hi*lo) for fp32-accurate logits.
// ---------------------------------------------------------------------------
__global__ __launch_bounds__(256) void attn(
        const unsigned short* __restrict__ qhi_ws, const unsigned short* __restrict__ qlo_ws,
        const unsigned short* __restrict__ khi_ws, const unsigned short* __restrict__ klo_ws,
        const unsigned short* __restrict__ vws, const float* __restrict__ x,
        float* __restrict__ out) {
    __shared__ unsigned short Klds[2][64 * 72];  // [hi/lo][j][d]
    __shared__ unsigned short Vlds[256 * 72];    // [c][j]  (reused fp32 in epilogue)
    __shared__ unsigned short Plds[64 * 72];     // [i][j]
    __shared__ float alpha_lds[64];
    __shared__ float l_lds[64];

    const int tid = threadIdx.x;
    const int b  = blockIdx.x >> 7;
    const int i0 = (blockIdx.x & 127) << 6;
    const int lane = tid & 63, w = tid >> 6;
    const int quad = lane >> 4, l16 = lane & 15;

    const unsigned short* qhb = qhi_ws + b * 8192 * 64;
    const unsigned short* qlb = qlo_ws + b * 8192 * 64;
    const unsigned short* khb = khi_ws + b * 8192 * 64;
    const unsigned short* klb = klo_ws + b * 8192 * 64;
    const unsigned short* vb  = vws + b * 256 * 8192;

    // Q fragments (wave owns rows i0 + w*16 .. +16)
    short8 qfh[2], qfl[2];
#pragma unroll
    for (int ks = 0; ks < 2; ++ks) {
        qfh[ks] = *reinterpret_cast<const short8*>(&qhb[(i0 + w * 16 + l16) * 64 + ks * 32 + quad * 8]);
        qfl[ks] = *reinterpret_cast<const short8*>(&qlb[(i0 + w * 16 + l16) * 64 + ks * 32 + quad * 8]);
    }

    float4v acc[4][4];
#pragma unroll
    for (int mt = 0; mt < 4; ++mt)
#pragma unroll
        for (int ct = 0; ct < 4; ++ct) acc[mt][ct] = (float4v){0.f, 0.f, 0.f, 0.f};
    float mrow[4] = {-1e30f, -1e30f, -1e30f, -1e30f};
    float lrow[4] = {0.f, 0.f, 0.f, 0.f};

    // Stage tile 0
    {
        int row = tid >> 3, seg = tid & 7;
#pragma unroll
        for (int p = 0; p < 2; ++p) {
            int r2 = row + p * 32;
            *reinterpret_cast<short8*>(&Klds[0][r2 * 72 + seg * 8]) =
                *reinterpret_cast<const short8*>(&khb[r2 * 64 + seg * 8]);
            *reinterpret_cast<short8*>(&Klds[1][r2 * 72 + seg * 8]) =
                *reinterpret_cast<const short8*>(&klb[r2 * 64 + seg * 8]);
        }
#pragma unroll
        for (int p = 0; p < 8; ++p) {
            int c = row + p * 32;
            *reinterpret_cast<short8*>(&Vlds[c * 72 + seg * 8]) =
                *reinterpret_cast<const short8*>(&vb[c * 8192 + seg * 8]);
        }
    }
    __syncthreads();

    for (int it = 0; it < 128; ++it) {
        const bool pf = (it < 127);
        const int j0n = (it + 1) << 6;
        short8 khstg[2], klstg[2], vstg[8];
        const int srow = tid >> 3, sseg = tid & 7;
        if (pf) {  // prefetch next K/V tile into registers (consumed after barrier 2)
#pragma unroll
            for (int p = 0; p < 2; ++p) {
                khstg[p] = *reinterpret_cast<const short8*>(&khb[(j0n + srow + p * 32) * 64 + sseg * 8]);
                klstg[p] = *reinterpret_cast<const short8*>(&klb[(j0n + srow + p * 32) * 64 + sseg * 8]);
            }
#pragma unroll
            for (int p = 0; p < 8; ++p)
                vstg[p] = *reinterpret_cast<const short8*>(&vb[(srow + p * 32) * 8192 + j0n + sseg * 8]);
        }

        // ---- QK^T (split-bf16): wave computes S[16 own rows][64 j] ----
        float4v s[4];
#pragma unroll
        for (int jt = 0; jt < 4; ++jt) s[jt] = (float4v){0.f, 0.f, 0.f, 0.f};
#pragma unroll
        for (int ks = 0; ks < 2; ++ks)
#pragma unroll
            for (int jt = 0; jt < 4; ++jt) {
                short8 bkh = *reinterpret_cast<const short8*>(&Klds[0][(jt * 16 + l16) * 72 + ks * 32 + quad * 8]);
                short8 bkl = *reinterpret_cast<const short8*>(&Klds[1][(jt * 16 + l16) * 72 + ks * 32 + quad * 8]);
                s[jt] = MFMA(qfh[ks], bkh, s[jt]);
                s[jt] = MFMA(qfl[ks], bkh, s[jt]);
                s[jt] = MFMA(qfh[ks], bkl, s[jt]);
            }

        // ---- online softmax (rows owned by this wave) ----
#pragma unroll
        for (int r = 0; r < 4; ++r) {
            float mx = fmaxf(fmaxf(s[0][r], s[1][r]), fmaxf(s[2][r], s[3][r]));
            mx = fmaxf(mx, __shfl_xor(mx, 1));
            mx = fmaxf(mx, __shfl_xor(mx, 2));
            mx = fmaxf(mx, __shfl_xor(mx, 4));
            mx = fmaxf(mx, __shfl_xor(mx, 8));
            float mn = fmaxf(mrow[r], mx);
            float al = __expf(mrow[r] - mn);
            mrow[r] = mn;
            float rs = 0.f;
#pragma unroll
            for (int jt = 0; jt < 4; ++jt) {
                float p_ = __expf(s[jt][r] - mn);
                unsigned short pb = f2bf(p_);
                rs += bf2f(pb);  // accumulate the SAME rounded weights PV uses
                Plds[(w * 16 + quad * 4 + r) * 72 + jt * 16 + l16] = pb;
            }
            lrow[r] = al * lrow[r] + rs;
            if (l16 == 0) alpha_lds[w * 16 + quad * 4 + r] = al;
        }
        __syncthreads();  // (1) P + alpha visible to all waves

        // ---- rescale O, then PV (wave owns c range [64w, 64w+64)) ----
        const int cb = w << 6;
        short8 aP[4][2];
#pragma unroll
        for (int mt = 0; mt < 4; ++mt)
#pragma unroll
            for (int ks = 0; ks < 2; ++ks)
                aP[mt][ks] = *reinterpret_cast<const short8*>(&Plds[(mt * 16 + l16) * 72 + ks * 32 + quad * 8]);
#pragma unroll
        for (int mt = 0; mt < 4; ++mt) {
            float av[4];
#pragma unroll
            for (int r = 0; r < 4; ++r) av[r] = alpha_lds[mt * 16 + quad * 4 + r];
#pragma unroll
            for (int ct = 0; ct < 4; ++ct)
#pragma unroll
                for (int r = 0; r < 4; ++r) acc[mt][ct][r] *= av[r];
        }
#pragma unroll
        for (int ct = 0; ct < 4; ++ct) {
            short8 bv0 = *reinterpret_cast<const short8*>(&Vlds[(cb + ct * 16 + l16) * 72 + quad * 8]);
            short8 bv1 = *reinterpret_cast<const short8*>(&Vlds[(cb + ct * 16 + l16) * 72 + 32 + quad * 8]);
#pragma unroll
            for (int mt = 0; mt < 4; ++mt) acc[mt][ct] = MFMA(aP[mt][0], bv0, acc[mt][ct]);
#pragma unroll
            for (int mt = 0; mt < 4; ++mt) acc[mt][ct] = MFMA(aP[mt][1], bv1, acc[mt][ct]);
        }
        __syncthreads();  // (2) all LDS reads of this tile done

        if (pf) {  // write prefetched tile into LDS
#pragma unroll
            for (int p = 0; p < 2; ++p) {
                *reinterpret_cast<short8*>(&Klds[0][(srow + p * 32) * 72 + sseg * 8]) = khstg[p];
                *reinterpret_cast<short8*>(&Klds[1][(srow + p * 32) * 72 + sseg * 8]) = klstg[p];
            }
#pragma unroll
            for (int p = 0; p < 8; ++p)
                *reinterpret_cast<short8*>(&Vlds[(srow + p * 32) * 72 + sseg * 8]) = vstg[p];
        }
        __syncthreads();  // (3) next tile ready
    }

    // ---- final l reduction ----
#pragma unroll
    for (int r = 0; r < 4; ++r) {
        float lv = lrow[r];
        lv += __shfl_xor(lv, 1);
        lv += __shfl_xor(lv, 2);
        lv += __shfl_xor(lv, 4);
        lv += __shfl_xor(lv, 8);
        if (l16 == 0) l_lds[w * 16 + quad * 4 + r] = lv;
    }
    __syncthreads();

    // ---- epilogue: O/l + x, via per-wave LDS transpose for coalesced I/O ----
    const float linv = 1.0f / l_lds[lane];
    float* ep = reinterpret_cast<float*>(Vlds) + w * (16 * 68);
    const float* xb2 = x + b * 256 * 8192;
    float* ob = out + b * 256 * 8192;
#pragma unroll 1
    for (int ct = 0; ct < 4; ++ct) {
#pragma unroll
        for (int mt = 0; mt < 4; ++mt)
#pragma unroll
            for (int r = 0; r < 4; ++r)
                ep[l16 * 68 + mt * 16 + quad * 4 + r] = acc[mt][ct][r];
        __syncthreads();
#pragma unroll 1
        for (int rr = 0; rr < 16; ++rr) {
            int c = (w << 6) + ct * 16 + rr;
            float o = ep[rr * 68 + lane] * linv;
            float xv = xb2[c * 8192 + i0 + lane];
            ob[c * 8192 + i0 + lane] = o + xv;
        }
        __syncthreads();
    }
}

// ---------------------------------------------------------------------------
extern "C" void kernel_launch(void* const* d_in, const int* in_sizes, int n_in,
                              void* d_out, int out_size, void* d_ws, size_t ws_size,
                              hipStream_t stream) {
    const float* x  = (const float*)d_in[0];
    const float* Wq = (const float*)d_in[1];
    const float* bq = (const float*)d_in[2];
    const float* Wk = (const float*)d_in[3];
    const float* bk = (const float*)d_in[4];
    const float* Wv = (const float*)d_in[5];
    const float* bv = (const float*)d_in[6];

    unsigned short* Whi = (unsigned short*)d_ws;           // 384*256
    unsigned short* Wlo = Whi + 384 * 256;                 // 128*256
    unsigned short* qhi = Wlo + 128 * 256;                 // [2][8192][64]
    unsigned short* qlo = qhi + 2 * 8192 * 64;
    unsigned short* khi = qlo + 2 * 8192 * 64;
    unsigned short* klo = khi + 2 * 8192 * 64;
    unsigned short* vws = klo + 2 * 8192 * 64;             // [2][256][8192]

    wcvt<<<384, 256, 0, stream>>>(Wq, Wk, Wv, Whi, Wlo);
    proj<<<256, 256, 0, stream>>>(x, Whi, Wlo, bq, bk, bv, qhi, qlo, khi, klo, vws);
    attn<<<256, 256, 0, stream>>>(qhi, qlo, khi, klo, vws, x, (float*)d_out);
}